// Round 18
// baseline (9093.290 us; speedup 1.0000x reference)
//
#include <hip/hip_runtime.h>

typedef unsigned short u16;
typedef float    f32x4  __attribute__((ext_vector_type(4)));
typedef _Float16 f16x8  __attribute__((ext_vector_type(8)));
typedef short    short8 __attribute__((ext_vector_type(8)));
typedef unsigned short u16x4 __attribute__((ext_vector_type(4)));

#define BB 16384
#define KK 30
#define NLAYER 90
#define ROWS 64
#define NBLK (BB / ROWS)     // 256 blocks = 1 per CU
#define THREADS 1024         // 16 waves

#define NT1 16        // phase-B N-tiles of 16 z-dims (240 -> 256; tile 15 zero)
#define KS1 5         // phase-B K-steps of 32 over concat cols 0..159
#define NT2 6         // phase-C N-tiles of 16 out-dims (96 padded)
#define KS2 8         // phase-C K-steps of 32 (240 -> 256 padded)

#define SZ1  (NLAYER * NT1 * KS1 * 512)   // u16 per plane
#define SZ23 (NLAYER * NT2 * KS2 * 512)   // u16 per plane
#define WS_NEEDED ((size_t)4 * (SZ1 + SZ23) + (size_t)4 * (NLAYER * 256 + NLAYER * 96))

// concat LDS cols: 0..29 Hr | 32..91 v | 96..125 t | 128..157 tH | rest zero
// STRIDES MUST BE MULTIPLES OF 8 u16 (16B) — ds_read_b128 alignment (R16).
#define A_STRIDE 168   // u16
#define Z_STRIDE 264   // u16
#define TO_STRIDE 36   // f32

#define MFMA16(a, b, c) __builtin_amdgcn_mfma_f32_16x16x32_f16((a), (b), (c), 0, 0, 0)

__device__ __forceinline__ void splitf(float x, u16& hi, u16& lo) {
    _Float16 h = (_Float16)x;
    _Float16 l = (_Float16)(x - (float)h);
    hi = __builtin_bit_cast(u16, h);
    lo = __builtin_bit_cast(u16, l);
}
__device__ __forceinline__ f16x8 ldfrag(const u16* p) {
    return __builtin_bit_cast(f16x8, *(const short8*)p);
}

// ---------------- prep: weights -> MFMA A-fragment layout (split fp16) -----
__global__ void prep(const float* __restrict__ W1, const float* __restrict__ W2,
                     const float* __restrict__ W3, const float* __restrict__ b1,
                     const float* __restrict__ b2, const float* __restrict__ b3,
                     u16* __restrict__ W1Fhi, u16* __restrict__ W1Flo,
                     u16* __restrict__ W23Fhi, u16* __restrict__ W23Flo,
                     float* __restrict__ b1p, float* __restrict__ b23p)
{
    int idx = blockIdx.x * 256 + threadIdx.x;
    if (idx < SZ1) {
        int j = idx & 7, lane = (idx >> 3) & 63;
        int r = idx >> 9, ks = r % 5; r /= 5;
        int nt = r % 16, l = r / 16;
        int kc = ks * 32 + (lane >> 4) * 8 + j;   // concat col
        int n  = nt * 16 + (lane & 15);           // z-dim
        float wv = 0.f;
        if (n < 240) {
            int k = -1;
            if      (kc < 30)               k = kc;        // Hr
            else if (kc >= 32 && kc < 92)   k = kc - 2;    // v
            else if (kc >= 96 && kc < 126)  k = kc - 6;    // t
            else if (kc >= 128 && kc < 158) k = kc - 8;    // tH
            if (k >= 0) wv = W1[((size_t)l * 240 + n) * 150 + k];
        }
        splitf(wv, W1Fhi[idx], W1Flo[idx]);
    }
    if (idx < SZ23) {
        int j = idx & 7, lane = (idx >> 3) & 63;
        int r = idx >> 9, ks = r % 8; r /= 8;
        int nt = r % 6, l = r / 6;
        int k = ks * 32 + (lane >> 4) * 8 + j;    // z-dim
        int n = nt * 16 + (lane & 15);            // out-dim (t 0..29, v 32..91)
        float wv = 0.f;
        if (k < 240) {
            if (n < 30)                 wv = W2[((size_t)l * 30 + n) * 240 + k];
            else if (n >= 32 && n < 92) wv = W3[((size_t)l * 60 + (n - 32)) * 240 + k];
        }
        splitf(wv, W23Fhi[idx], W23Flo[idx]);
    }
    if (idx < NLAYER * 256) {
        int l = idx >> 8, c = idx & 255;
        b1p[idx] = (c < 240) ? b1[l * 240 + c] : 0.f;
    }
    if (idx < NLAYER * 96) {
        int l = idx / 96, c = idx % 96;
        b23p[idx] = (c < 30) ? b2[l * 30 + c]
                  : ((c >= 32 && c < 92) ? b3[l * 60 + (c - 32)] : 0.f);
    }
}

// ---------------- main persistent kernel (16 waves, 64 rows / block) --------
// Layer schedule (3 barriers, A+D co-scheduled under B's MFMAs):
//   phase 1: D(l-1) | A(l) | B ks0..3  (ks0..3 read cols 0..127 only;
//            A writes tH cols 128..157 — disjoint, no race)
//   barrier  -> tH visible
//   phase 2: C-weight prefetch to regs | B ks4 (reads tH) + z epilogue
//   barrier  -> zT visible
//   phase 3: C (weights already in regs) ; writes t/v/tOut
//   barrier  -> state visible for next layer
__global__ __launch_bounds__(THREADS, 4)
void detnet_kernel(const float* __restrict__ Hr, const float* __restrict__ HH,
                   const float* __restrict__ kappa,
                   const u16* __restrict__ W1Fhi, const u16* __restrict__ W1Flo,
                   const u16* __restrict__ W23Fhi, const u16* __restrict__ W23Flo,
                   const float* __restrict__ b1p, const float* __restrict__ b23p,
                   float* __restrict__ out)
{
    __shared__ u16 aT_hi[ROWS][A_STRIDE], aT_lo[ROWS][A_STRIDE];
    __shared__ u16 zT_hi[ROWS][Z_STRIDE], zT_lo[ROWS][Z_STRIDE];
    __shared__ float tOut[ROWS][TO_STRIDE];

    const int tid  = threadIdx.x;
    const int b0   = blockIdx.x * ROWS;
    const int w    = tid >> 6;       // 0..15
    const int lane = tid & 63;
    const int h    = lane >> 4;
    const int q    = lane & 15;

    // phase-C mapping (waves 0..11): 6 out-tiles x 2 batch-halves
    const int cnt = w >> 1;
    const int cmh = w & 1;

    // phase-A mapping + persistent HH registers (fp32 — REQUIRED precision:
    // fp16 HH failed at 2.9e-2 in R13; all recurrence operands need > fp16)
    const int ra = tid >> 4;         // 0..63
    const int sa = tid & 15;         // sa<15 active
    float2 hreg[KK];
    if (sa < 15) {
        const float* hh = HH + (size_t)(b0 + ra) * (KK * KK) + 2 * sa;
        #pragma unroll
        for (int k = 0; k < KK; ++k) hreg[k] = *(const float2*)(hh + k * KK);
    } else {
        #pragma unroll
        for (int k = 0; k < KK; ++k) hreg[k] = make_float2(0.f, 0.f);
    }

    // phase-C persistent state (waves 0..11): t_tilde or v, [mm][reg]
    float st[2][4];
    #pragma unroll
    for (int m = 0; m < 2; ++m)
        #pragma unroll
        for (int r = 0; r < 4; ++r) st[m][r] = 0.f;

    // ---- init LDS ----
    for (int i = tid; i < ROWS * A_STRIDE; i += THREADS) { (&aT_hi[0][0])[i] = 0; (&aT_lo[0][0])[i] = 0; }
    for (int i = tid; i < ROWS * Z_STRIDE; i += THREADS) { (&zT_hi[0][0])[i] = 0; (&zT_lo[0][0])[i] = 0; }
    for (int i = tid; i < ROWS * TO_STRIDE; i += THREADS) (&tOut[0][0])[i] = 0.f;
    __syncthreads();
    for (int i = tid; i < ROWS * KK; i += THREADS) {
        int r = i / KK, k = i - r * KK;
        splitf(Hr[(size_t)(b0 + r) * KK + k], aT_hi[r][k], aT_lo[r][k]);
    }
    __syncthreads();

    for (int l = 0; l < NLAYER; ++l) {
        // ================= phase 1 : D(l-1) | A(l) | B ks0..3 =================
        f32x4 acc[4];
        {
            f32x4 bb = *(const f32x4*)&b1p[l * 256 + w * 16 + 4 * h];
            #pragma unroll
            for (int m = 0; m < 4; ++m) acc[m] = bb;
        }

        // D: NT store of t(l-1)
        if (l > 0 && tid < ROWS * KK / 4) {
            f32x4 o;
            int e = tid * 4;
            #pragma unroll
            for (int i = 0; i < 4; ++i) {
                int ee = e + i, r = ee / 30, k2 = ee - 30 * r;
                o[i] = tOut[r][k2];
            }
            __builtin_nontemporal_store(o, (f32x4*)(out + ((size_t)(l - 1) * BB + b0) * KK + e));
        }

        // A: tH = t . HH (fp32 register FMA); writes cols 128..157 only
        if (l > 0 && sa < 15) {
            float a0 = 0.f, a1 = 0.f;
            #pragma unroll
            for (int k = 0; k < KK; ++k) {
                float tk = tOut[ra][k];
                a0 += tk * hreg[k].x;
                a1 += tk * hreg[k].y;
            }
            u16 h0, l0, h1, l1;
            splitf(a0, h0, l0); splitf(a1, h1, l1);
            *(unsigned int*)&aT_hi[ra][128 + 2 * sa] = (unsigned int)h0 | ((unsigned int)h1 << 16);
            *(unsigned int*)&aT_lo[ra][128 + 2 * sa] = (unsigned int)l0 | ((unsigned int)l1 << 16);
        }

        // B ks0..3: reads cols 0..127 (Hr/v/t — valid since prev C-barrier)
        #pragma unroll
        for (int ks = 0; ks < 4; ++ks) {
            size_t off = ((((size_t)l * NT1 + w) * KS1 + ks) * 64 + lane) * 8;
            f16x8 wh = ldfrag(W1Fhi + off);
            f16x8 wl = ldfrag(W1Flo + off);
            #pragma unroll
            for (int m = 0; m < 4; ++m) {
                f16x8 ah = ldfrag(&aT_hi[m * 16 + q][ks * 32 + h * 8]);
                f16x8 al = ldfrag(&aT_lo[m * 16 + q][ks * 32 + h * 8]);
                acc[m] = MFMA16(wh, ah, acc[m]);
                acc[m] = MFMA16(wl, ah, acc[m]);
                acc[m] = MFMA16(wh, al, acc[m]);
            }
        }
        __syncthreads();   // tH visible

        // ================= phase 2 : C-prefetch | B ks4 + epilogue ============
        f16x8 cwh[KS2], cwl[KS2];
        if (w < 12) {
            #pragma unroll
            for (int ks = 0; ks < KS2; ++ks) {
                size_t off = ((((size_t)l * NT2 + cnt) * KS2 + ks) * 64 + lane) * 8;
                cwh[ks] = ldfrag(W23Fhi + off);
                cwl[ks] = ldfrag(W23Flo + off);
            }
        }
        {
            const int ks = 4;   // reads cols 128..159 = tH
            size_t off = ((((size_t)l * NT1 + w) * KS1 + ks) * 64 + lane) * 8;
            f16x8 wh = ldfrag(W1Fhi + off);
            f16x8 wl = ldfrag(W1Flo + off);
            #pragma unroll
            for (int m = 0; m < 4; ++m) {
                f16x8 ah = ldfrag(&aT_hi[m * 16 + q][ks * 32 + h * 8]);
                f16x8 al = ldfrag(&aT_lo[m * 16 + q][ks * 32 + h * 8]);
                acc[m] = MFMA16(wh, ah, acc[m]);
                acc[m] = MFMA16(wl, ah, acc[m]);
                acc[m] = MFMA16(wh, al, acc[m]);
            }
        }
        #pragma unroll
        for (int m = 0; m < 4; ++m) {
            u16x4 zh, zl;
            #pragma unroll
            for (int reg = 0; reg < 4; ++reg) {
                float zv = fmaxf(acc[m][reg], 0.f);
                u16 a, b; splitf(zv, a, b);
                zh[reg] = a; zl[reg] = b;
            }
            *(u16x4*)&zT_hi[m * 16 + q][w * 16 + 4 * h] = zh;
            *(u16x4*)&zT_lo[m * 16 + q][w * 16 + 4 * h] = zl;
        }
        __syncthreads();   // zT visible

        // ================= phase 3 : C (weights pre-loaded) ===================
        if (w < 12) {
            const float kap = kappa[l];
            const float inv = 1.0f / fabsf(kap);
            f32x4 cacc[2];
            {
                f32x4 bb = *(const f32x4*)&b23p[l * 96 + cnt * 16 + 4 * h];
                cacc[0] = bb; cacc[1] = bb;
            }
            #pragma unroll 4
            for (int ks = 0; ks < KS2; ++ks) {
                #pragma unroll
                for (int mm = 0; mm < 2; ++mm) {
                    f16x8 zh = ldfrag(&zT_hi[(cmh * 2 + mm) * 16 + q][ks * 32 + h * 8]);
                    f16x8 zl = ldfrag(&zT_lo[(cmh * 2 + mm) * 16 + q][ks * 32 + h * 8]);
                    cacc[mm] = MFMA16(cwh[ks], zh, cacc[mm]);
                    cacc[mm] = MFMA16(cwl[ks], zh, cacc[mm]);
                    cacc[mm] = MFMA16(cwh[ks], zl, cacc[mm]);
                }
            }
            const int nbase = cnt * 16 + 4 * h;
            #pragma unroll
            for (int mm = 0; mm < 2; ++mm) {
                const int brow = (cmh * 2 + mm) * 16 + q;
                if (nbase + 3 < 30) {
                    f32x4 tn4;
                    u16x4 th, tl;
                    #pragma unroll
                    for (int reg = 0; reg < 4; ++reg) {
                        float s2 = st[mm][reg] + cacc[mm][reg];
                        st[mm][reg] = s2;
                        float tn = -1.0f + fmaxf(s2 + kap, 0.f) * inv - fmaxf(s2 - kap, 0.f) * inv;
                        tn4[reg] = tn;
                        u16 a, b; splitf(tn, a, b);
                        th[reg] = a; tl[reg] = b;
                    }
                    *(f32x4*)&tOut[brow][nbase] = tn4;
                    *(u16x4*)&aT_hi[brow][96 + nbase] = th;
                    *(u16x4*)&aT_lo[brow][96 + nbase] = tl;
                } else if (nbase < 30) {
                    #pragma unroll
                    for (int reg = 0; reg < 2; ++reg) {
                        float s2 = st[mm][reg] + cacc[mm][reg];
                        st[mm][reg] = s2;
                        float tn = -1.0f + fmaxf(s2 + kap, 0.f) * inv - fmaxf(s2 - kap, 0.f) * inv;
                        tOut[brow][nbase + reg] = tn;
                        splitf(tn, aT_hi[brow][96 + nbase + reg], aT_lo[brow][96 + nbase + reg]);
                    }
                } else if (nbase >= 32 && nbase + 3 < 92) {
                    u16x4 vh, vl;
                    #pragma unroll
                    for (int reg = 0; reg < 4; ++reg) {
                        float s2 = st[mm][reg] + cacc[mm][reg];
                        st[mm][reg] = s2;
                        u16 a, b; splitf(s2, a, b);
                        vh[reg] = a; vl[reg] = b;
                    }
                    *(u16x4*)&aT_hi[brow][nbase] = vh;
                    *(u16x4*)&aT_lo[brow][nbase] = vl;
                }
            }
        }
        __syncthreads();   // state visible for next layer
    }

    // final output layer 89
    if (tid < ROWS * KK / 4) {
        f32x4 o;
        int e = tid * 4;
        #pragma unroll
        for (int i = 0; i < 4; ++i) {
            int ee = e + i, r = ee / 30, k2 = ee - 30 * r;
            o[i] = tOut[r][k2];
        }
        __builtin_nontemporal_store(o, (f32x4*)(out + ((size_t)(NLAYER - 1) * BB + b0) * KK + e));
    }
}

extern "C" void kernel_launch(void* const* d_in, const int* in_sizes, int n_in,
                              void* d_out, int out_size, void* d_ws, size_t ws_size,
                              hipStream_t stream) {
    const float* Hr = (const float*)d_in[0];
    const float* HH = (const float*)d_in[1];
    const float* W1 = (const float*)d_in[2];
    const float* b1 = (const float*)d_in[3];
    const float* W2 = (const float*)d_in[4];
    const float* b2 = (const float*)d_in[5];
    const float* W3 = (const float*)d_in[6];
    const float* b3 = (const float*)d_in[7];
    const float* kp = (const float*)d_in[8];
    float* out = (float*)d_out;

    if (ws_size < WS_NEEDED) return;

    u16* W1Fhi  = (u16*)d_ws;
    u16* W1Flo  = W1Fhi + SZ1;
    u16* W23Fhi = W1Flo + SZ1;
    u16* W23Flo = W23Fhi + SZ23;
    float* b1p  = (float*)(W23Flo + SZ23);
    float* b23p = b1p + NLAYER * 256;

    prep<<<dim3((SZ1 + 255) / 256), dim3(256), 0, stream>>>(
        W1, W2, W3, b1, b2, b3, W1Fhi, W1Flo, W23Fhi, W23Flo, b1p, b23p);
    detnet_kernel<<<dim3(NBLK), dim3(THREADS), 0, stream>>>(
        Hr, HH, kp, W1Fhi, W1Flo, W23Fhi, W23Flo, b1p, b23p, out);
}

// Round 19
// 744.769 us; speedup vs baseline: 12.2096x; 12.2096x over previous
//
#include <hip/hip_runtime.h>

typedef unsigned short u16;
typedef float    f32x4  __attribute__((ext_vector_type(4)));
typedef _Float16 f16x8  __attribute__((ext_vector_type(8)));
typedef short    short8 __attribute__((ext_vector_type(8)));
typedef unsigned short u16x4 __attribute__((ext_vector_type(4)));

#define BB 16384
#define KK 30
#define NLAYER 90
#define ROWS 64
#define NBLK (BB / ROWS)     // 256 blocks = 1 per CU
#define THREADS 1024         // 16 waves

#define NT1 16        // phase-B N-tile slots (only 15 real: z-dims 0..239)
#define KS1 5         // phase-B K-steps of 32 over concat cols 0..159
#define NT2 6         // phase-C N-tiles of 16 out-dims (96 padded)
#define KS2 8         // phase-C K-steps of 32 (240 -> 256 padded)

#define SZ1  (NLAYER * NT1 * KS1 * 512)   // u16 per plane
#define SZ23 (NLAYER * NT2 * KS2 * 512)   // u16 per plane
#define WS_NEEDED ((size_t)4 * (SZ1 + SZ23) + (size_t)4 * (NLAYER * 256 + NLAYER * 96))

// concat LDS cols: 0..29 Hr | 32..91 v | 96..125 t | 128..157 tH | rest zero
// STRIDES MUST BE MULTIPLES OF 8 u16 (16B) — ds_read_b128 alignment (R16).
#define A_STRIDE 168   // u16
#define Z_STRIDE 264   // u16
#define TO_STRIDE 36   // f32

#define MFMA16(a, b, c) __builtin_amdgcn_mfma_f32_16x16x32_f16((a), (b), (c), 0, 0, 0)

__device__ __forceinline__ void splitf(float x, u16& hi, u16& lo) {
    _Float16 h = (_Float16)x;
    _Float16 l = (_Float16)(x - (float)h);
    hi = __builtin_bit_cast(u16, h);
    lo = __builtin_bit_cast(u16, l);
}
__device__ __forceinline__ f16x8 ldfrag(const u16* p) {
    return __builtin_bit_cast(f16x8, *(const short8*)p);
}

// ---------------- prep: weights -> MFMA A-fragment layout (split fp16) -----
__global__ void prep(const float* __restrict__ W1, const float* __restrict__ W2,
                     const float* __restrict__ W3, const float* __restrict__ b1,
                     const float* __restrict__ b2, const float* __restrict__ b3,
                     u16* __restrict__ W1Fhi, u16* __restrict__ W1Flo,
                     u16* __restrict__ W23Fhi, u16* __restrict__ W23Flo,
                     float* __restrict__ b1p, float* __restrict__ b23p)
{
    int idx = blockIdx.x * 256 + threadIdx.x;
    if (idx < SZ1) {
        int j = idx & 7, lane = (idx >> 3) & 63;
        int r = idx >> 9, ks = r % 5; r /= 5;
        int nt = r % 16, l = r / 16;
        int kc = ks * 32 + (lane >> 4) * 8 + j;   // concat col
        int n  = nt * 16 + (lane & 15);           // z-dim
        float wv = 0.f;
        if (n < 240) {
            int k = -1;
            if      (kc < 30)               k = kc;        // Hr
            else if (kc >= 32 && kc < 92)   k = kc - 2;    // v
            else if (kc >= 96 && kc < 126)  k = kc - 6;    // t
            else if (kc >= 128 && kc < 158) k = kc - 8;    // tH
            if (k >= 0) wv = W1[((size_t)l * 240 + n) * 150 + k];
        }
        splitf(wv, W1Fhi[idx], W1Flo[idx]);
    }
    if (idx < SZ23) {
        int j = idx & 7, lane = (idx >> 3) & 63;
        int r = idx >> 9, ks = r % 8; r /= 8;
        int nt = r % 6, l = r / 6;
        int k = ks * 32 + (lane >> 4) * 8 + j;    // z-dim
        int n = nt * 16 + (lane & 15);            // out-dim (t 0..29, v 32..91)
        float wv = 0.f;
        if (k < 240) {
            if (n < 30)                 wv = W2[((size_t)l * 30 + n) * 240 + k];
            else if (n >= 32 && n < 92) wv = W3[((size_t)l * 60 + (n - 32)) * 240 + k];
        }
        splitf(wv, W23Fhi[idx], W23Flo[idx]);
    }
    if (idx < NLAYER * 256) {
        int l = idx >> 8, c = idx & 255;
        b1p[idx] = (c < 240) ? b1[l * 240 + c] : 0.f;
    }
    if (idx < NLAYER * 96) {
        int l = idx / 96, c = idx % 96;
        b23p[idx] = (c < 30) ? b2[l * 30 + c]
                  : ((c >= 32 && c < 92) ? b3[l * 60 + (c - 32)] : 0.f);
    }
}

// ---------------- main persistent kernel (16 waves, 64 rows / block) --------
// Wave 15's phase-B tile (z-dims 240..255) is all-zero padding: it is SKIPPED
// (zT cols 240+ stay zero from init; W23 k>=240 fragments are zero anyway).
// The D-store (out write of t(l-1)) is reassigned to wave 15, so it no longer
// competes with B-active waves for issue slots / VMEM.
__global__ __launch_bounds__(THREADS, 4)
void detnet_kernel(const float* __restrict__ Hr, const float* __restrict__ HH,
                   const float* __restrict__ kappa,
                   const u16* __restrict__ W1Fhi, const u16* __restrict__ W1Flo,
                   const u16* __restrict__ W23Fhi, const u16* __restrict__ W23Flo,
                   const float* __restrict__ b1p, const float* __restrict__ b23p,
                   float* __restrict__ out)
{
    __shared__ u16 aT_hi[ROWS][A_STRIDE], aT_lo[ROWS][A_STRIDE];
    __shared__ u16 zT_hi[ROWS][Z_STRIDE], zT_lo[ROWS][Z_STRIDE];
    __shared__ float tOut[ROWS][TO_STRIDE];

    const int tid  = threadIdx.x;
    const int b0   = blockIdx.x * ROWS;
    const int w    = tid >> 6;       // 0..15
    const int lane = tid & 63;
    const int h    = lane >> 4;
    const int q    = lane & 15;

    // phase-C mapping (waves 0..11): 6 out-tiles x 2 batch-halves
    const int cnt = w >> 1;
    const int cmh = w & 1;

    // phase-A mapping + persistent HH registers (fp32 — REQUIRED precision:
    // fp16 HH failed at 2.9e-2 in R13; all recurrence operands need > fp16)
    const int ra = tid >> 4;         // 0..63
    const int sa = tid & 15;         // sa<15 active
    float2 hreg[KK];
    if (sa < 15) {
        const float* hh = HH + (size_t)(b0 + ra) * (KK * KK) + 2 * sa;
        #pragma unroll
        for (int k = 0; k < KK; ++k) hreg[k] = *(const float2*)(hh + k * KK);
    } else {
        #pragma unroll
        for (int k = 0; k < KK; ++k) hreg[k] = make_float2(0.f, 0.f);
    }

    // phase-C persistent state (waves 0..11): t_tilde or v, [mm][reg]
    float st[2][4];
    #pragma unroll
    for (int m = 0; m < 2; ++m)
        #pragma unroll
        for (int r = 0; r < 4; ++r) st[m][r] = 0.f;

    // ---- init LDS ----
    for (int i = tid; i < ROWS * A_STRIDE; i += THREADS) { (&aT_hi[0][0])[i] = 0; (&aT_lo[0][0])[i] = 0; }
    for (int i = tid; i < ROWS * Z_STRIDE; i += THREADS) { (&zT_hi[0][0])[i] = 0; (&zT_lo[0][0])[i] = 0; }
    for (int i = tid; i < ROWS * TO_STRIDE; i += THREADS) (&tOut[0][0])[i] = 0.f;
    __syncthreads();
    for (int i = tid; i < ROWS * KK; i += THREADS) {
        int r = i / KK, k = i - r * KK;
        splitf(Hr[(size_t)(b0 + r) * KK + k], aT_hi[r][k], aT_lo[r][k]);
    }
    __syncthreads();

    for (int l = 0; l < NLAYER; ++l) {
        // ---- phase D (prev layer): NT store of t — wave 15 only (idle in B) ----
        if (l > 0 && w == 15) {
            for (int s = tid - 960; s < ROWS * KK / 4; s += 64) {
                f32x4 o;
                int e = s * 4;
                #pragma unroll
                for (int i = 0; i < 4; ++i) {
                    int ee = e + i, r = ee / 30, k2 = ee - 30 * r;
                    o[i] = tOut[r][k2];
                }
                __builtin_nontemporal_store(o, (f32x4*)(out + ((size_t)(l - 1) * BB + b0) * KK + e));
            }
        }

        // ---- phase A : tH = t . HH, pure fp32 register FMA ----
        if (l > 0 && sa < 15) {
            float a0 = 0.f, a1 = 0.f;
            #pragma unroll
            for (int k = 0; k < KK; ++k) {
                float tk = tOut[ra][k];
                a0 += tk * hreg[k].x;
                a1 += tk * hreg[k].y;
            }
            u16 h0, l0, h1, l1;
            splitf(a0, h0, l0); splitf(a1, h1, l1);
            *(unsigned int*)&aT_hi[ra][128 + 2 * sa] = (unsigned int)h0 | ((unsigned int)h1 << 16);
            *(unsigned int*)&aT_lo[ra][128 + 2 * sa] = (unsigned int)l0 | ((unsigned int)l1 << 16);
        }
        __syncthreads();

        // ---- phase B : z^T = W1 . concat^T ; waves 0..14 (tile 15 is zero pad).
        //      Wave = 1 z-tile x 4 batch-tiles; D: col=batch row, row=z-dim ----
        if (w < 15) {
            f32x4 acc[4];
            {
                f32x4 bb = *(const f32x4*)&b1p[l * 256 + w * 16 + 4 * h];
                #pragma unroll
                for (int m = 0; m < 4; ++m) acc[m] = bb;
            }
            #pragma unroll
            for (int ks = 0; ks < KS1; ++ks) {
                size_t off = ((((size_t)l * NT1 + w) * KS1 + ks) * 64 + lane) * 8;
                f16x8 wh = ldfrag(W1Fhi + off);
                f16x8 wl = ldfrag(W1Flo + off);
                #pragma unroll
                for (int m = 0; m < 4; ++m) {
                    f16x8 ah = ldfrag(&aT_hi[m * 16 + q][ks * 32 + h * 8]);
                    f16x8 al = ldfrag(&aT_lo[m * 16 + q][ks * 32 + h * 8]);
                    acc[m] = MFMA16(wh, ah, acc[m]);
                    acc[m] = MFMA16(wl, ah, acc[m]);
                    acc[m] = MFMA16(wh, al, acc[m]);
                }
            }
            #pragma unroll
            for (int m = 0; m < 4; ++m) {
                u16x4 zh, zl;
                #pragma unroll
                for (int reg = 0; reg < 4; ++reg) {
                    float zv = fmaxf(acc[m][reg], 0.f);
                    u16 a, b; splitf(zv, a, b);
                    zh[reg] = a; zl[reg] = b;
                }
                *(u16x4*)&zT_hi[m * 16 + q][w * 16 + 4 * h] = zh;
                *(u16x4*)&zT_lo[m * 16 + q][w * 16 + 4 * h] = zl;
            }
        }
        __syncthreads();

        // ---- phase C : (dtt|dv)^T = W23 . z^T + state update (waves 0..11) ----
        if (w < 12) {
            const float kap = kappa[l];
            const float inv = 1.0f / fabsf(kap);
            f32x4 acc[2];
            {
                f32x4 bb = *(const f32x4*)&b23p[l * 96 + cnt * 16 + 4 * h];
                acc[0] = bb; acc[1] = bb;
            }
            #pragma unroll 4
            for (int ks = 0; ks < KS2; ++ks) {
                size_t off = ((((size_t)l * NT2 + cnt) * KS2 + ks) * 64 + lane) * 8;
                f16x8 wh = ldfrag(W23Fhi + off);
                f16x8 wl = ldfrag(W23Flo + off);
                #pragma unroll
                for (int mm = 0; mm < 2; ++mm) {
                    f16x8 zh = ldfrag(&zT_hi[(cmh * 2 + mm) * 16 + q][ks * 32 + h * 8]);
                    f16x8 zl = ldfrag(&zT_lo[(cmh * 2 + mm) * 16 + q][ks * 32 + h * 8]);
                    acc[mm] = MFMA16(wh, zh, acc[mm]);
                    acc[mm] = MFMA16(wl, zh, acc[mm]);
                    acc[mm] = MFMA16(wh, zl, acc[mm]);
                }
            }
            const int nbase = cnt * 16 + 4 * h;
            #pragma unroll
            for (int mm = 0; mm < 2; ++mm) {
                const int brow = (cmh * 2 + mm) * 16 + q;
                if (nbase + 3 < 30) {
                    f32x4 tn4;
                    u16x4 th, tl;
                    #pragma unroll
                    for (int reg = 0; reg < 4; ++reg) {
                        float s2 = st[mm][reg] + acc[mm][reg];
                        st[mm][reg] = s2;
                        float tn = -1.0f + fmaxf(s2 + kap, 0.f) * inv - fmaxf(s2 - kap, 0.f) * inv;
                        tn4[reg] = tn;
                        u16 a, b; splitf(tn, a, b);
                        th[reg] = a; tl[reg] = b;
                    }
                    *(f32x4*)&tOut[brow][nbase] = tn4;
                    *(u16x4*)&aT_hi[brow][96 + nbase] = th;
                    *(u16x4*)&aT_lo[brow][96 + nbase] = tl;
                } else if (nbase < 30) {
                    #pragma unroll
                    for (int reg = 0; reg < 2; ++reg) {
                        float s2 = st[mm][reg] + acc[mm][reg];
                        st[mm][reg] = s2;
                        float tn = -1.0f + fmaxf(s2 + kap, 0.f) * inv - fmaxf(s2 - kap, 0.f) * inv;
                        tOut[brow][nbase + reg] = tn;
                        splitf(tn, aT_hi[brow][96 + nbase + reg], aT_lo[brow][96 + nbase + reg]);
                    }
                } else if (nbase >= 32 && nbase + 3 < 92) {
                    u16x4 vh, vl;
                    #pragma unroll
                    for (int reg = 0; reg < 4; ++reg) {
                        float s2 = st[mm][reg] + acc[mm][reg];
                        st[mm][reg] = s2;
                        u16 a, b; splitf(s2, a, b);
                        vh[reg] = a; vl[reg] = b;
                    }
                    *(u16x4*)&aT_hi[brow][nbase] = vh;
                    *(u16x4*)&aT_lo[brow][nbase] = vl;
                }
            }
        }
        __syncthreads();
    }

    // final output layer 89 (all threads — no overlap to exploit here)
    if (tid < ROWS * KK / 4) {
        f32x4 o;
        int e = tid * 4;
        #pragma unroll
        for (int i = 0; i < 4; ++i) {
            int ee = e + i, r = ee / 30, k2 = ee - 30 * r;
            o[i] = tOut[r][k2];
        }
        __builtin_nontemporal_store(o, (f32x4*)(out + ((size_t)(NLAYER - 1) * BB + b0) * KK + e));
    }
}

extern "C" void kernel_launch(void* const* d_in, const int* in_sizes, int n_in,
                              void* d_out, int out_size, void* d_ws, size_t ws_size,
                              hipStream_t stream) {
    const float* Hr = (const float*)d_in[0];
    const float* HH = (const float*)d_in[1];
    const float* W1 = (const float*)d_in[2];
    const float* b1 = (const float*)d_in[3];
    const float* W2 = (const float*)d_in[4];
    const float* b2 = (const float*)d_in[5];
    const float* W3 = (const float*)d_in[6];
    const float* b3 = (const float*)d_in[7];
    const float* kp = (const float*)d_in[8];
    float* out = (float*)d_out;

    if (ws_size < WS_NEEDED) return;

    u16* W1Fhi  = (u16*)d_ws;
    u16* W1Flo  = W1Fhi + SZ1;
    u16* W23Fhi = W1Flo + SZ1;
    u16* W23Flo = W23Fhi + SZ23;
    float* b1p  = (float*)(W23Flo + SZ23);
    float* b23p = b1p + NLAYER * 256;

    prep<<<dim3((SZ1 + 255) / 256), dim3(256), 0, stream>>>(
        W1, W2, W3, b1, b2, b3, W1Fhi, W1Flo, W23Fhi, W23Flo, b1p, b23p);
    detnet_kernel<<<dim3(NBLK), dim3(THREADS), 0, stream>>>(
        Hr, HH, kp, W1Fhi, W1Flo, W23Fhi, W23Flo, b1p, b23p, out);
}

// Round 20
// 732.475 us; speedup vs baseline: 12.4145x; 1.0168x over previous
//
#include <hip/hip_runtime.h>

typedef unsigned short u16;
typedef float    f32x4  __attribute__((ext_vector_type(4)));
typedef _Float16 f16x8  __attribute__((ext_vector_type(8)));
typedef short    short8 __attribute__((ext_vector_type(8)));
typedef unsigned short u16x4 __attribute__((ext_vector_type(4)));

#define BB 16384
#define KK 30
#define NLAYER 90
#define ROWS 64
#define NBLK (BB / ROWS)     // 256 blocks = 1 per CU
#define THREADS 1024         // 16 waves

#define NT1 16        // phase-B N-tiles of 16 z-dims (240 -> 256; tile 15 zero)
#define KS1 5         // phase-B K-steps of 32 over concat cols 0..159
#define NT2 6         // phase-C N-tiles of 16 out-dims (96 padded)
#define KS2 8         // phase-C K-steps of 32 (240 -> 256 padded)

#define SZ1  (NLAYER * NT1 * KS1 * 512)   // u16 per plane
#define SZ23 (NLAYER * NT2 * KS2 * 512)   // u16 per plane
#define WS_NEEDED ((size_t)4 * (SZ1 + SZ23) + (size_t)4 * (NLAYER * 256 + NLAYER * 96))

// concat LDS cols: 0..29 Hr | 32..91 v | 96..125 t | 128..157 tH | rest zero
// STRIDES MUST BE MULTIPLES OF 8 u16 (16B) — ds_read_b128 alignment (R16).
#define A_STRIDE 168   // u16
#define Z_STRIDE 264   // u16
#define TO_STRIDE 36   // f32

#define MFMA16(a, b, c) __builtin_amdgcn_mfma_f32_16x16x32_f16((a), (b), (c), 0, 0, 0)

__device__ __forceinline__ void splitf(float x, u16& hi, u16& lo) {
    _Float16 h = (_Float16)x;
    _Float16 l = (_Float16)(x - (float)h);
    hi = __builtin_bit_cast(u16, h);
    lo = __builtin_bit_cast(u16, l);
}
__device__ __forceinline__ f16x8 ldfrag(const u16* p) {
    return __builtin_bit_cast(f16x8, *(const short8*)p);
}

// ---------------- prep: weights -> MFMA A-fragment layout (split fp16) -----
__global__ void prep(const float* __restrict__ W1, const float* __restrict__ W2,
                     const float* __restrict__ W3, const float* __restrict__ b1,
                     const float* __restrict__ b2, const float* __restrict__ b3,
                     u16* __restrict__ W1Fhi, u16* __restrict__ W1Flo,
                     u16* __restrict__ W23Fhi, u16* __restrict__ W23Flo,
                     float* __restrict__ b1p, float* __restrict__ b23p)
{
    int idx = blockIdx.x * 256 + threadIdx.x;
    if (idx < SZ1) {
        int j = idx & 7, lane = (idx >> 3) & 63;
        int r = idx >> 9, ks = r % 5; r /= 5;
        int nt = r % 16, l = r / 16;
        int kc = ks * 32 + (lane >> 4) * 8 + j;   // concat col
        int n  = nt * 16 + (lane & 15);           // z-dim
        float wv = 0.f;
        if (n < 240) {
            int k = -1;
            if      (kc < 30)               k = kc;        // Hr
            else if (kc >= 32 && kc < 92)   k = kc - 2;    // v
            else if (kc >= 96 && kc < 126)  k = kc - 6;    // t
            else if (kc >= 128 && kc < 158) k = kc - 8;    // tH
            if (k >= 0) wv = W1[((size_t)l * 240 + n) * 150 + k];
        }
        splitf(wv, W1Fhi[idx], W1Flo[idx]);
    }
    if (idx < SZ23) {
        int j = idx & 7, lane = (idx >> 3) & 63;
        int r = idx >> 9, ks = r % 8; r /= 8;
        int nt = r % 6, l = r / 6;
        int k = ks * 32 + (lane >> 4) * 8 + j;    // z-dim
        int n = nt * 16 + (lane & 15);            // out-dim (t 0..29, v 32..91)
        float wv = 0.f;
        if (k < 240) {
            if (n < 30)                 wv = W2[((size_t)l * 30 + n) * 240 + k];
            else if (n >= 32 && n < 92) wv = W3[((size_t)l * 60 + (n - 32)) * 240 + k];
        }
        splitf(wv, W23Fhi[idx], W23Flo[idx]);
    }
    if (idx < NLAYER * 256) {
        int l = idx >> 8, c = idx & 255;
        b1p[idx] = (c < 240) ? b1[l * 240 + c] : 0.f;
    }
    if (idx < NLAYER * 96) {
        int l = idx / 96, c = idx % 96;
        b23p[idx] = (c < 30) ? b2[l * 30 + c]
                  : ((c >= 32 && c < 92) ? b3[l * 60 + (c - 32)] : 0.f);
    }
}

// ---------------- main persistent kernel (16 waves, 64 rows / block) --------
// Layer schedule (3 barriers; A+D co-scheduled under B ks0..3 — the ONLY
// cross-barrier live state is acc[4] (16 VGPRs), unlike R18 whose 64-reg
// C-weight prefetch spilled):
//   phase 1: D(l-1) | A(l) | B ks0..3  (B reads cols 0..127; A writes 128..157)
//   barrier  -> tH visible
//   phase 2: B ks4 (reads tH) + z epilogue
//   barrier  -> zT visible
//   phase 3: C (direct weight loads, as R17)
//   barrier  -> state visible for next layer
__global__ __launch_bounds__(THREADS, 4)
void detnet_kernel(const float* __restrict__ Hr, const float* __restrict__ HH,
                   const float* __restrict__ kappa,
                   const u16* __restrict__ W1Fhi, const u16* __restrict__ W1Flo,
                   const u16* __restrict__ W23Fhi, const u16* __restrict__ W23Flo,
                   const float* __restrict__ b1p, const float* __restrict__ b23p,
                   float* __restrict__ out)
{
    __shared__ u16 aT_hi[ROWS][A_STRIDE], aT_lo[ROWS][A_STRIDE];
    __shared__ u16 zT_hi[ROWS][Z_STRIDE], zT_lo[ROWS][Z_STRIDE];
    __shared__ float tOut[ROWS][TO_STRIDE];

    const int tid  = threadIdx.x;
    const int b0   = blockIdx.x * ROWS;
    const int w    = tid >> 6;       // 0..15
    const int lane = tid & 63;
    const int h    = lane >> 4;
    const int q    = lane & 15;

    // phase-C mapping (waves 0..11): 6 out-tiles x 2 batch-halves
    const int cnt = w >> 1;
    const int cmh = w & 1;

    // phase-A mapping + persistent HH registers (fp32 — REQUIRED precision:
    // fp16 HH failed at 2.9e-2 in R13; all recurrence operands need > fp16)
    const int ra = tid >> 4;         // 0..63
    const int sa = tid & 15;         // sa<15 active
    float2 hreg[KK];
    if (sa < 15) {
        const float* hh = HH + (size_t)(b0 + ra) * (KK * KK) + 2 * sa;
        #pragma unroll
        for (int k = 0; k < KK; ++k) hreg[k] = *(const float2*)(hh + k * KK);
    } else {
        #pragma unroll
        for (int k = 0; k < KK; ++k) hreg[k] = make_float2(0.f, 0.f);
    }

    // phase-C persistent state (waves 0..11): t_tilde or v, [mm][reg]
    float st[2][4];
    #pragma unroll
    for (int m = 0; m < 2; ++m)
        #pragma unroll
        for (int r = 0; r < 4; ++r) st[m][r] = 0.f;

    // ---- init LDS ----
    for (int i = tid; i < ROWS * A_STRIDE; i += THREADS) { (&aT_hi[0][0])[i] = 0; (&aT_lo[0][0])[i] = 0; }
    for (int i = tid; i < ROWS * Z_STRIDE; i += THREADS) { (&zT_hi[0][0])[i] = 0; (&zT_lo[0][0])[i] = 0; }
    for (int i = tid; i < ROWS * TO_STRIDE; i += THREADS) (&tOut[0][0])[i] = 0.f;
    __syncthreads();
    for (int i = tid; i < ROWS * KK; i += THREADS) {
        int r = i / KK, k = i - r * KK;
        splitf(Hr[(size_t)(b0 + r) * KK + k], aT_hi[r][k], aT_lo[r][k]);
    }
    __syncthreads();

    for (int l = 0; l < NLAYER; ++l) {
        // ================= phase 1 : D(l-1) | A(l) | B ks0..3 =================
        f32x4 acc[4];
        {
            f32x4 bb = *(const f32x4*)&b1p[l * 256 + w * 16 + 4 * h];
            #pragma unroll
            for (int m = 0; m < 4; ++m) acc[m] = bb;
        }

        // D: NT store of t(l-1) — spread over 240 threads (R17 placement;
        // R19 showed concentrating it on one wave serializes phase 1)
        if (l > 0 && tid < ROWS * KK / 4) {
            f32x4 o;
            int e = tid * 4;
            #pragma unroll
            for (int i = 0; i < 4; ++i) {
                int ee = e + i, r = ee / 30, k2 = ee - 30 * r;
                o[i] = tOut[r][k2];
            }
            __builtin_nontemporal_store(o, (f32x4*)(out + ((size_t)(l - 1) * BB + b0) * KK + e));
        }

        // A: tH = t . HH (fp32 register FMA); writes cols 128..157 only
        if (l > 0 && sa < 15) {
            float a0 = 0.f, a1 = 0.f;
            #pragma unroll
            for (int k = 0; k < KK; ++k) {
                float tk = tOut[ra][k];
                a0 += tk * hreg[k].x;
                a1 += tk * hreg[k].y;
            }
            u16 h0, l0, h1, l1;
            splitf(a0, h0, l0); splitf(a1, h1, l1);
            *(unsigned int*)&aT_hi[ra][128 + 2 * sa] = (unsigned int)h0 | ((unsigned int)h1 << 16);
            *(unsigned int*)&aT_lo[ra][128 + 2 * sa] = (unsigned int)l0 | ((unsigned int)l1 << 16);
        }

        // B ks0..3: reads cols 0..127 (Hr/v/t — valid since prev C-barrier)
        #pragma unroll
        for (int ks = 0; ks < 4; ++ks) {
            size_t off = ((((size_t)l * NT1 + w) * KS1 + ks) * 64 + lane) * 8;
            f16x8 wh = ldfrag(W1Fhi + off);
            f16x8 wl = ldfrag(W1Flo + off);
            #pragma unroll
            for (int m = 0; m < 4; ++m) {
                f16x8 ah = ldfrag(&aT_hi[m * 16 + q][ks * 32 + h * 8]);
                f16x8 al = ldfrag(&aT_lo[m * 16 + q][ks * 32 + h * 8]);
                acc[m] = MFMA16(wh, ah, acc[m]);
                acc[m] = MFMA16(wl, ah, acc[m]);
                acc[m] = MFMA16(wh, al, acc[m]);
            }
        }
        __syncthreads();   // tH visible

        // ================= phase 2 : B ks4 (tH) + z epilogue ==================
        {
            const int ks = 4;   // reads cols 128..159 = tH (+2 zero pad)
            size_t off = ((((size_t)l * NT1 + w) * KS1 + ks) * 64 + lane) * 8;
            f16x8 wh = ldfrag(W1Fhi + off);
            f16x8 wl = ldfrag(W1Flo + off);
            #pragma unroll
            for (int m = 0; m < 4; ++m) {
                f16x8 ah = ldfrag(&aT_hi[m * 16 + q][ks * 32 + h * 8]);
                f16x8 al = ldfrag(&aT_lo[m * 16 + q][ks * 32 + h * 8]);
                acc[m] = MFMA16(wh, ah, acc[m]);
                acc[m] = MFMA16(wl, ah, acc[m]);
                acc[m] = MFMA16(wh, al, acc[m]);
            }
        }
        #pragma unroll
        for (int m = 0; m < 4; ++m) {
            u16x4 zh, zl;
            #pragma unroll
            for (int reg = 0; reg < 4; ++reg) {
                float zv = fmaxf(acc[m][reg], 0.f);
                u16 a, b; splitf(zv, a, b);
                zh[reg] = a; zl[reg] = b;
            }
            *(u16x4*)&zT_hi[m * 16 + q][w * 16 + 4 * h] = zh;
            *(u16x4*)&zT_lo[m * 16 + q][w * 16 + 4 * h] = zl;
        }
        __syncthreads();   // zT visible

        // ================= phase 3 : C (direct weight loads, as R17) ==========
        if (w < 12) {
            const float kap = kappa[l];
            const float inv = 1.0f / fabsf(kap);
            f32x4 cacc[2];
            {
                f32x4 bb = *(const f32x4*)&b23p[l * 96 + cnt * 16 + 4 * h];
                cacc[0] = bb; cacc[1] = bb;
            }
            #pragma unroll 4
            for (int ks = 0; ks < KS2; ++ks) {
                size_t off = ((((size_t)l * NT2 + cnt) * KS2 + ks) * 64 + lane) * 8;
                f16x8 wh = ldfrag(W23Fhi + off);
                f16x8 wl = ldfrag(W23Flo + off);
                #pragma unroll
                for (int mm = 0; mm < 2; ++mm) {
                    f16x8 zh = ldfrag(&zT_hi[(cmh * 2 + mm) * 16 + q][ks * 32 + h * 8]);
                    f16x8 zl = ldfrag(&zT_lo[(cmh * 2 + mm) * 16 + q][ks * 32 + h * 8]);
                    cacc[mm] = MFMA16(wh, zh, cacc[mm]);
                    cacc[mm] = MFMA16(wl, zh, cacc[mm]);
                    cacc[mm] = MFMA16(wh, zl, cacc[mm]);
                }
            }
            const int nbase = cnt * 16 + 4 * h;
            #pragma unroll
            for (int mm = 0; mm < 2; ++mm) {
                const int brow = (cmh * 2 + mm) * 16 + q;
                if (nbase + 3 < 30) {
                    f32x4 tn4;
                    u16x4 th, tl;
                    #pragma unroll
                    for (int reg = 0; reg < 4; ++reg) {
                        float s2 = st[mm][reg] + cacc[mm][reg];
                        st[mm][reg] = s2;
                        float tn = -1.0f + fmaxf(s2 + kap, 0.f) * inv - fmaxf(s2 - kap, 0.f) * inv;
                        tn4[reg] = tn;
                        u16 a, b; splitf(tn, a, b);
                        th[reg] = a; tl[reg] = b;
                    }
                    *(f32x4*)&tOut[brow][nbase] = tn4;
                    *(u16x4*)&aT_hi[brow][96 + nbase] = th;
                    *(u16x4*)&aT_lo[brow][96 + nbase] = tl;
                } else if (nbase < 30) {
                    #pragma unroll
                    for (int reg = 0; reg < 2; ++reg) {
                        float s2 = st[mm][reg] + cacc[mm][reg];
                        st[mm][reg] = s2;
                        float tn = -1.0f + fmaxf(s2 + kap, 0.f) * inv - fmaxf(s2 - kap, 0.f) * inv;
                        tOut[brow][nbase + reg] = tn;
                        splitf(tn, aT_hi[brow][96 + nbase + reg], aT_lo[brow][96 + nbase + reg]);
                    }
                } else if (nbase >= 32 && nbase + 3 < 92) {
                    u16x4 vh, vl;
                    #pragma unroll
                    for (int reg = 0; reg < 4; ++reg) {
                        float s2 = st[mm][reg] + cacc[mm][reg];
                        st[mm][reg] = s2;
                        u16 a, b; splitf(s2, a, b);
                        vh[reg] = a; vl[reg] = b;
                    }
                    *(u16x4*)&aT_hi[brow][nbase] = vh;
                    *(u16x4*)&aT_lo[brow][nbase] = vl;
                }
            }
        }
        __syncthreads();   // state visible for next layer
    }

    // final output layer 89
    if (tid < ROWS * KK / 4) {
        f32x4 o;
        int e = tid * 4;
        #pragma unroll
        for (int i = 0; i < 4; ++i) {
            int ee = e + i, r = ee / 30, k2 = ee - 30 * r;
            o[i] = tOut[r][k2];
        }
        __builtin_nontemporal_store(o, (f32x4*)(out + ((size_t)(NLAYER - 1) * BB + b0) * KK + e));
    }
}

extern "C" void kernel_launch(void* const* d_in, const int* in_sizes, int n_in,
                              void* d_out, int out_size, void* d_ws, size_t ws_size,
                              hipStream_t stream) {
    const float* Hr = (const float*)d_in[0];
    const float* HH = (const float*)d_in[1];
    const float* W1 = (const float*)d_in[2];
    const float* b1 = (const float*)d_in[3];
    const float* W2 = (const float*)d_in[4];
    const float* b2 = (const float*)d_in[5];
    const float* W3 = (const float*)d_in[6];
    const float* b3 = (const float*)d_in[7];
    const float* kp = (const float*)d_in[8];
    float* out = (float*)d_out;

    if (ws_size < WS_NEEDED) return;

    u16* W1Fhi  = (u16*)d_ws;
    u16* W1Flo  = W1Fhi + SZ1;
    u16* W23Fhi = W1Flo + SZ1;
    u16* W23Flo = W23Fhi + SZ23;
    float* b1p  = (float*)(W23Flo + SZ23);
    float* b23p = b1p + NLAYER * 256;

    prep<<<dim3((SZ1 + 255) / 256), dim3(256), 0, stream>>>(
        W1, W2, W3, b1, b2, b3, W1Fhi, W1Flo, W23Fhi, W23Flo, b1p, b23p);
    detnet_kernel<<<dim3(NBLK), dim3(THREADS), 0, stream>>>(
        Hr, HH, kp, W1Fhi, W1Flo, W23Fhi, W23Flo, b1p, b23p, out);
}

// Round 21
// 710.976 us; speedup vs baseline: 12.7899x; 1.0302x over previous
//
#include <hip/hip_runtime.h>

typedef unsigned short u16;
typedef float    f32x4  __attribute__((ext_vector_type(4)));
typedef _Float16 f16x8  __attribute__((ext_vector_type(8)));
typedef short    short8 __attribute__((ext_vector_type(8)));
typedef unsigned short u16x4 __attribute__((ext_vector_type(4)));

#define BB 16384
#define KK 30
#define NLAYER 90
#define ROWS 64
#define NBLK (BB / ROWS)     // 256 blocks = 1 per CU
#define THREADS 1024         // 16 waves

#define NT1 16        // phase-B N-tiles of 16 z-dims (240 -> 256; tile 15 zero)
#define KS1 5         // phase-B K-steps of 32 over concat cols 0..159
#define NT2 6         // phase-C N-tiles of 16 out-dims (96 padded)
#define KS2 8         // phase-C K-steps of 32 (240 -> 256 padded)

#define SZ1  (NLAYER * NT1 * KS1 * 512)   // u16 per plane
#define SZ23 (NLAYER * NT2 * KS2 * 512)   // u16 per plane
#define WS_NEEDED ((size_t)4 * (SZ1 + SZ23) + (size_t)4 * (NLAYER * 256 + NLAYER * 96))

// concat LDS cols: 0..29 Hr | 32..91 v | 96..125 t | 128..157 tH | rest zero
// STRIDES MUST BE MULTIPLES OF 8 u16 (16B) — ds_read_b128 alignment (R16).
#define A_STRIDE 168   // u16
#define Z_STRIDE 264   // u16
#define TO_STRIDE 36   // f32

#define MFMA16(a, b, c) __builtin_amdgcn_mfma_f32_16x16x32_f16((a), (b), (c), 0, 0, 0)

__device__ __forceinline__ void splitf(float x, u16& hi, u16& lo) {
    _Float16 h = (_Float16)x;
    _Float16 l = (_Float16)(x - (float)h);
    hi = __builtin_bit_cast(u16, h);
    lo = __builtin_bit_cast(u16, l);
}
__device__ __forceinline__ f16x8 ldfrag(const u16* p) {
    return __builtin_bit_cast(f16x8, *(const short8*)p);
}

// ---------------- prep: weights -> MFMA A-fragment layout (split fp16) -----
__global__ void prep(const float* __restrict__ W1, const float* __restrict__ W2,
                     const float* __restrict__ W3, const float* __restrict__ b1,
                     const float* __restrict__ b2, const float* __restrict__ b3,
                     u16* __restrict__ W1Fhi, u16* __restrict__ W1Flo,
                     u16* __restrict__ W23Fhi, u16* __restrict__ W23Flo,
                     float* __restrict__ b1p, float* __restrict__ b23p)
{
    int idx = blockIdx.x * 256 + threadIdx.x;
    if (idx < SZ1) {
        int j = idx & 7, lane = (idx >> 3) & 63;
        int r = idx >> 9, ks = r % 5; r /= 5;
        int nt = r % 16, l = r / 16;
        int kc = ks * 32 + (lane >> 4) * 8 + j;   // concat col
        int n  = nt * 16 + (lane & 15);           // z-dim
        float wv = 0.f;
        if (n < 240) {
            int k = -1;
            if      (kc < 30)               k = kc;        // Hr
            else if (kc >= 32 && kc < 92)   k = kc - 2;    // v
            else if (kc >= 96 && kc < 126)  k = kc - 6;    // t
            else if (kc >= 128 && kc < 158) k = kc - 8;    // tH
            if (k >= 0) wv = W1[((size_t)l * 240 + n) * 150 + k];
        }
        splitf(wv, W1Fhi[idx], W1Flo[idx]);
    }
    if (idx < SZ23) {
        int j = idx & 7, lane = (idx >> 3) & 63;
        int r = idx >> 9, ks = r % 8; r /= 8;
        int nt = r % 6, l = r / 6;
        int k = ks * 32 + (lane >> 4) * 8 + j;    // z-dim
        int n = nt * 16 + (lane & 15);            // out-dim (t 0..29, v 32..91)
        float wv = 0.f;
        if (k < 240) {
            if (n < 30)                 wv = W2[((size_t)l * 30 + n) * 240 + k];
            else if (n >= 32 && n < 92) wv = W3[((size_t)l * 60 + (n - 32)) * 240 + k];
        }
        splitf(wv, W23Fhi[idx], W23Flo[idx]);
    }
    if (idx < NLAYER * 256) {
        int l = idx >> 8, c = idx & 255;
        b1p[idx] = (c < 240) ? b1[l * 240 + c] : 0.f;
    }
    if (idx < NLAYER * 96) {
        int l = idx / 96, c = idx % 96;
        b23p[idx] = (c < 30) ? b2[l * 30 + c]
                  : ((c >= 32 && c < 92) ? b3[l * 60 + (c - 32)] : 0.f);
    }
}

// ---------------- main persistent kernel (16 waves, 64 rows / block) --------
__global__ __launch_bounds__(THREADS, 4)
void detnet_kernel(const float* __restrict__ Hr, const float* __restrict__ HH,
                   const float* __restrict__ kappa,
                   const u16* __restrict__ W1Fhi, const u16* __restrict__ W1Flo,
                   const u16* __restrict__ W23Fhi, const u16* __restrict__ W23Flo,
                   const float* __restrict__ b1p, const float* __restrict__ b23p,
                   float* __restrict__ out)
{
    __shared__ u16 aT_hi[ROWS][A_STRIDE], aT_lo[ROWS][A_STRIDE];
    __shared__ u16 zT_hi[ROWS][Z_STRIDE], zT_lo[ROWS][Z_STRIDE];
    __shared__ float tOut[ROWS][TO_STRIDE];

    const int tid  = threadIdx.x;
    const int b0   = blockIdx.x * ROWS;
    const int w    = tid >> 6;       // 0..15
    const int lane = tid & 63;
    const int h    = lane >> 4;
    const int q    = lane & 15;

    // phase-C mapping (waves 0..11): 6 out-tiles x 2 batch-halves
    const int cnt = w >> 1;
    const int cmh = w & 1;

    // phase-A mapping + persistent HH registers (fp32 — REQUIRED precision:
    // fp16 HH failed at 2.9e-2 in R13; all recurrence operands need > fp16)
    const int ra = tid >> 4;         // 0..63
    const int sa = tid & 15;         // sa<15 active
    float2 hreg[KK];
    if (sa < 15) {
        const float* hh = HH + (size_t)(b0 + ra) * (KK * KK) + 2 * sa;
        #pragma unroll
        for (int k = 0; k < KK; ++k) hreg[k] = *(const float2*)(hh + k * KK);
    } else {
        #pragma unroll
        for (int k = 0; k < KK; ++k) hreg[k] = make_float2(0.f, 0.f);
    }

    // phase-C persistent state (waves 0..11): t_tilde or v, [mm][reg]
    float st[2][4];
    #pragma unroll
    for (int m = 0; m < 2; ++m)
        #pragma unroll
        for (int r = 0; r < 4; ++r) st[m][r] = 0.f;

    // ---- init LDS ----
    for (int i = tid; i < ROWS * A_STRIDE; i += THREADS) { (&aT_hi[0][0])[i] = 0; (&aT_lo[0][0])[i] = 0; }
    for (int i = tid; i < ROWS * Z_STRIDE; i += THREADS) { (&zT_hi[0][0])[i] = 0; (&zT_lo[0][0])[i] = 0; }
    for (int i = tid; i < ROWS * TO_STRIDE; i += THREADS) (&tOut[0][0])[i] = 0.f;
    __syncthreads();
    for (int i = tid; i < ROWS * KK; i += THREADS) {
        int r = i / KK, k = i - r * KK;
        splitf(Hr[(size_t)(b0 + r) * KK + k], aT_hi[r][k], aT_lo[r][k]);
    }
    __syncthreads();

    for (int l = 0; l < NLAYER; ++l) {
        // ---- phase D (prev layer): NT store of t ----
        if (l > 0 && tid < ROWS * KK / 4) {
            f32x4 o;
            int e = tid * 4;
            #pragma unroll
            for (int i = 0; i < 4; ++i) {
                int ee = e + i, r = ee / 30, k2 = ee - 30 * r;
                o[i] = tOut[r][k2];
            }
            __builtin_nontemporal_store(o, (f32x4*)(out + ((size_t)(l - 1) * BB + b0) * KK + e));
        }

        // ---- phase A : tH = t . HH, pure fp32 register FMA ----
        if (l > 0 && sa < 15) {
            float a0 = 0.f, a1 = 0.f;
            #pragma unroll
            for (int k = 0; k < KK; ++k) {
                float tk = tOut[ra][k];
                a0 += tk * hreg[k].x;
                a1 += tk * hreg[k].y;
            }
            u16 h0, l0, h1, l1;
            splitf(a0, h0, l0); splitf(a1, h1, l1);
            *(unsigned int*)&aT_hi[ra][128 + 2 * sa] = (unsigned int)h0 | ((unsigned int)h1 << 16);
            *(unsigned int*)&aT_lo[ra][128 + 2 * sa] = (unsigned int)l0 | ((unsigned int)l1 << 16);
        }
        __syncthreads();

        // ---- phase B : z^T = W1 . concat^T ; wave = 1 z-tile x 4 batch-tiles.
        //      D: col=lane&15=batch row, row=4h+reg = z-dim (consecutive!) ----
        {
            f32x4 acc[4];
            {
                f32x4 bb = *(const f32x4*)&b1p[l * 256 + w * 16 + 4 * h];
                #pragma unroll
                for (int m = 0; m < 4; ++m) acc[m] = bb;
            }
            #pragma unroll
            for (int ks = 0; ks < KS1; ++ks) {
                size_t off = ((((size_t)l * NT1 + w) * KS1 + ks) * 64 + lane) * 8;
                f16x8 wh = ldfrag(W1Fhi + off);
                f16x8 wl = ldfrag(W1Flo + off);
                #pragma unroll
                for (int m = 0; m < 4; ++m) {
                    f16x8 ah = ldfrag(&aT_hi[m * 16 + q][ks * 32 + h * 8]);
                    f16x8 al = ldfrag(&aT_lo[m * 16 + q][ks * 32 + h * 8]);
                    acc[m] = MFMA16(wh, ah, acc[m]);
                    acc[m] = MFMA16(wl, ah, acc[m]);
                    acc[m] = MFMA16(wh, al, acc[m]);
                }
            }
            #pragma unroll
            for (int m = 0; m < 4; ++m) {
                u16x4 zh, zl;
                #pragma unroll
                for (int reg = 0; reg < 4; ++reg) {
                    float zv = fmaxf(acc[m][reg], 0.f);
                    u16 a, b; splitf(zv, a, b);
                    zh[reg] = a; zl[reg] = b;
                }
                *(u16x4*)&zT_hi[m * 16 + q][w * 16 + 4 * h] = zh;
                *(u16x4*)&zT_lo[m * 16 + q][w * 16 + 4 * h] = zl;
            }
        }
        __syncthreads();

        // ---- phase C : (dtt|dv)^T = W23 . z^T + state update (waves 0..11) ----
        if (w < 12) {
            const float kap = kappa[l];
            const float inv = 1.0f / fabsf(kap);
            f32x4 acc[2];
            {
                f32x4 bb = *(const f32x4*)&b23p[l * 96 + cnt * 16 + 4 * h];
                acc[0] = bb; acc[1] = bb;
            }
            #pragma unroll 4
            for (int ks = 0; ks < KS2; ++ks) {
                size_t off = ((((size_t)l * NT2 + cnt) * KS2 + ks) * 64 + lane) * 8;
                f16x8 wh = ldfrag(W23Fhi + off);
                f16x8 wl = ldfrag(W23Flo + off);
                #pragma unroll
                for (int mm = 0; mm < 2; ++mm) {
                    f16x8 zh = ldfrag(&zT_hi[(cmh * 2 + mm) * 16 + q][ks * 32 + h * 8]);
                    f16x8 zl = ldfrag(&zT_lo[(cmh * 2 + mm) * 16 + q][ks * 32 + h * 8]);
                    acc[mm] = MFMA16(wh, zh, acc[mm]);
                    acc[mm] = MFMA16(wl, zh, acc[mm]);
                    acc[mm] = MFMA16(wh, zl, acc[mm]);
                }
            }
            const int nbase = cnt * 16 + 4 * h;
            #pragma unroll
            for (int mm = 0; mm < 2; ++mm) {
                const int brow = (cmh * 2 + mm) * 16 + q;
                if (nbase + 3 < 30) {
                    f32x4 tn4;
                    u16x4 th, tl;
                    #pragma unroll
                    for (int reg = 0; reg < 4; ++reg) {
                        float s2 = st[mm][reg] + acc[mm][reg];
                        st[mm][reg] = s2;
                        float tn = -1.0f + fmaxf(s2 + kap, 0.f) * inv - fmaxf(s2 - kap, 0.f) * inv;
                        tn4[reg] = tn;
                        u16 a, b; splitf(tn, a, b);
                        th[reg] = a; tl[reg] = b;
                    }
                    *(f32x4*)&tOut[brow][nbase] = tn4;
                    *(u16x4*)&aT_hi[brow][96 + nbase] = th;
                    *(u16x4*)&aT_lo[brow][96 + nbase] = tl;
                } else if (nbase < 30) {
                    #pragma unroll
                    for (int reg = 0; reg < 2; ++reg) {
                        float s2 = st[mm][reg] + acc[mm][reg];
                        st[mm][reg] = s2;
                        float tn = -1.0f + fmaxf(s2 + kap, 0.f) * inv - fmaxf(s2 - kap, 0.f) * inv;
                        tOut[brow][nbase + reg] = tn;
                        splitf(tn, aT_hi[brow][96 + nbase + reg], aT_lo[brow][96 + nbase + reg]);
                    }
                } else if (nbase >= 32 && nbase + 3 < 92) {
                    u16x4 vh, vl;
                    #pragma unroll
                    for (int reg = 0; reg < 4; ++reg) {
                        float s2 = st[mm][reg] + acc[mm][reg];
                        st[mm][reg] = s2;
                        u16 a, b; splitf(s2, a, b);
                        vh[reg] = a; vl[reg] = b;
                    }
                    *(u16x4*)&aT_hi[brow][nbase] = vh;
                    *(u16x4*)&aT_lo[brow][nbase] = vl;
                }
            }
        }
        __syncthreads();
    }

    // final output layer 89
    if (tid < ROWS * KK / 4) {
        f32x4 o;
        int e = tid * 4;
        #pragma unroll
        for (int i = 0; i < 4; ++i) {
            int ee = e + i, r = ee / 30, k2 = ee - 30 * r;
            o[i] = tOut[r][k2];
        }
        __builtin_nontemporal_store(o, (f32x4*)(out + ((size_t)(NLAYER - 1) * BB + b0) * KK + e));
    }
}

extern "C" void kernel_launch(void* const* d_in, const int* in_sizes, int n_in,
                              void* d_out, int out_size, void* d_ws, size_t ws_size,
                              hipStream_t stream) {
    const float* Hr = (const float*)d_in[0];
    const float* HH = (const float*)d_in[1];
    const float* W1 = (const float*)d_in[2];
    const float* b1 = (const float*)d_in[3];
    const float* W2 = (const float*)d_in[4];
    const float* b2 = (const float*)d_in[5];
    const float* W3 = (const float*)d_in[6];
    const float* b3 = (const float*)d_in[7];
    const float* kp = (const float*)d_in[8];
    float* out = (float*)d_out;

    if (ws_size < WS_NEEDED) return;

    u16* W1Fhi  = (u16*)d_ws;
    u16* W1Flo  = W1Fhi + SZ1;
    u16* W23Fhi = W1Flo + SZ1;
    u16* W23Flo = W23Fhi + SZ23;
    float* b1p  = (float*)(W23Flo + SZ23);
    float* b23p = b1p + NLAYER * 256;

    prep<<<dim3((SZ1 + 255) / 256), dim3(256), 0, stream>>>(
        W1, W2, W3, b1, b2, b3, W1Fhi, W1Flo, W23Fhi, W23Flo, b1p, b23p);
    detnet_kernel<<<dim3(NBLK), dim3(THREADS), 0, stream>>>(
        Hr, HH, kp, W1Fhi, W1Flo, W23Fhi, W23Flo, b1p, b23p, out);
}